// Round 12
// baseline (529.284 us; speedup 1.0000x reference)
//
#include <hip/hip_runtime.h>
#include <stdint.h>

#define N_NODES 65536
#define N_EDGES 1048576
#define BATCH   128
#define PD      512
#define CLIPD   768

typedef __attribute__((ext_vector_type(4))) float f32x4;
typedef __attribute__((ext_vector_type(2))) float f32x2;
typedef __attribute__((ext_vector_type(4))) int   i32x4;

__device__ __forceinline__ unsigned short f2b(float f) {
    uint32_t u = __float_as_uint(f);
    return (unsigned short)((u + 0x7fffu + ((u >> 16) & 1u)) >> 16);
}

// fp4 e2m1 pack (2 floats -> byte0) / unpack (byte0 -> 2 floats), scale = 1.0 (identity)
__device__ __forceinline__ uint32_t pk_fp4(float x, float y, float one) {
    uint32_t r = 0;
    asm("v_cvt_scalef32_pk_fp4_f32 %0, %1, %2, %3" : "+v"(r) : "v"(x), "v"(y), "v"(one));
    return r;
}
__device__ __forceinline__ f32x2 upk_fp4(uint32_t b, float one) {
    f32x2 r;
    asm("v_cvt_scalef32_pk_f32_fp4 %0, %1, %2" : "=v"(r) : "v"(b), "v"(one));
    return r;
}

// ---------------- Wg transpose+cast to bf16; batch counts via binary search on sorted bv ----------------
__global__ void k_wgt(const float* __restrict__ Wg, unsigned short* __restrict__ WgT,
                      const int* __restrict__ bv, int* __restrict__ cnts) {
    __shared__ float tile[32][33];
    int kb = blockIdx.x * 32, nb = blockIdx.y * 32;
    int tx = threadIdx.x, ty = threadIdx.y;
    if (kb == 0 && nb == 0) {
        int tid = ty * 32 + tx;
        if (tid < BATCH) {
            int lo = 0, hi = N_NODES;
            while (lo < hi) { int m = (lo + hi) >> 1; if (bv[m] < tid) lo = m + 1; else hi = m; }
            int lo2 = lo, hi2 = N_NODES;
            while (lo2 < hi2) { int m = (lo2 + hi2) >> 1; if (bv[m] < tid + 1) lo2 = m + 1; else hi2 = m; }
            cnts[tid] = lo2 - lo;
        }
    }
    tile[ty][tx] = Wg[(size_t)(kb + ty) * PD + nb + tx];
    __syncthreads();
    WgT[(size_t)(nb + ty) * PD + kb + tx] = f2b(tile[tx][ty]);
}

// ---------------- degree count over dst (deg = #non-self in-edges; zeroed via memset) ----------------
__global__ void k_deg(const int* __restrict__ ei, int* __restrict__ deg) {
    int e = blockIdx.x * 256 + threadIdx.x;   // E threads
    atomicAdd(&deg[ei[N_EDGES + e]], 1);
}

// ---------------- coalesced wave-scan: row_ptr = exclusive scan of deg; dis = rsqrt(deg+1) ----------------
__global__ void k_scan(const int* __restrict__ deg, int* __restrict__ row_ptr,
                       float* __restrict__ dis) {
    __shared__ int wsum[16];
    const int t = threadIdx.x;            // 1024
    const int w = t >> 6, l = t & 63;
    const int base = w * 4096;            // contiguous region per wave
    int s = 0;
    for (int i = 0; i < 64; ++i) s += deg[base + i * 64 + l];
#pragma unroll
    for (int off = 1; off < 64; off <<= 1) s += __shfl_xor(s, off);
    if (l == 0) wsum[w] = s;
    __syncthreads();
    int carry = 0;
    for (int i = 0; i < 16; ++i) carry += (i < w) ? wsum[i] : 0;
    int idx = base + l;
    int d = deg[idx];
    for (int i = 0; i < 64; ++i) {
        int dn = 0;
        if (i < 63) dn = deg[idx + 64];
        int v = d;
        int inc = v;
#pragma unroll
        for (int off = 1; off < 64; off <<= 1) {
            int n = __shfl_up(inc, off);
            if (l >= off) inc += n;
        }
        row_ptr[idx] = carry + inc - v;
        dis[idx] = rsqrtf((float)(d + 1));
        carry += __shfl(inc, 63);
        idx += 64;
        d = dn;
    }
    if (t == 1023) row_ptr[N_NODES] = carry;  // == E
}

// ---------------- scatter edges into CSR buckets ----------------
__global__ void k_scatter(const int* __restrict__ ei, const int* __restrict__ row_ptr,
                          int* __restrict__ fill, int* __restrict__ srcs) {
    int e = blockIdx.x * 256 + threadIdx.x;
    int d = ei[N_EDGES + e];
    int pos = row_ptr[d] + atomicAdd(&fill[d], 1);
    srcs[pos] = ei[e];
}

// ---------------- big GEMM: hn4 = fp4( 16 * dis[i] * (x[i] @ Wg) ) ----------------
// 128x256 tile, BK=32, 4 waves. fp4 row layout (256B): byte b holds cols ((b>>4)*32+(b&15), +16).
// FIX vs r10: byte index includes n0/2 (was racing/garbage for blockIdx.y=1).
__device__ __forceinline__ void mfma16(f32x4& acc, i32x4 a, i32x4 b) {
    asm("v_mfma_f32_16x16x32_bf16 %0, %1, %2, %0" : "+v"(acc) : "v"(a), "v"(b));
}

__global__ __launch_bounds__(256) void k_gemm(const float* __restrict__ X,
                                              const unsigned short* __restrict__ WgT,
                                              const float* __restrict__ dis,
                                              uint8_t* __restrict__ hn4) {
    __shared__ __align__(16) unsigned short As[128 * 32];
    __shared__ __align__(16) unsigned short Bs[256 * 32];
    const int m0 = blockIdx.x * 128;
    const int n0 = blockIdx.y * 256;
    const int t = threadIdx.x;
    const int lane = t & 63, w = t >> 6;
    const int wr = w >> 1, wc = w & 1;       // wave tile: 64 rows x 128 cols
    const int g = lane >> 4, lr = lane & 15;

    f32x4 acc[4][8] = {};

    for (int k0 = 0; k0 < PD; k0 += 32) {
        __syncthreads();
#pragma unroll
        for (int it = 0; it < 4; ++it) {
            int idx = it * 256 + t;
            int r = idx >> 3, kc = (idx & 7) * 4;
            float4 v = *(const float4*)&X[(size_t)(m0 + r) * PD + k0 + kc];
            uint2 o;
            o.x = (uint32_t)f2b(v.x) | ((uint32_t)f2b(v.y) << 16);
            o.y = (uint32_t)f2b(v.z) | ((uint32_t)f2b(v.w) << 16);
            *(uint2*)&As[r * 32 + kc] = o;
        }
#pragma unroll
        for (int it = 0; it < 4; ++it) {
            int idx = it * 256 + t;
            int r = idx >> 2, kc = (idx & 3) * 8;
            *(uint4*)&Bs[r * 32 + kc] = *(const uint4*)&WgT[(size_t)(n0 + r) * PD + k0 + kc];
        }
        __syncthreads();

        i32x4 a[4], b[8];
#pragma unroll
        for (int i = 0; i < 4; ++i) a[i] = *(const i32x4*)&As[(wr * 64 + i * 16 + lr) * 32 + g * 8];
#pragma unroll
        for (int j = 0; j < 8; ++j) b[j] = *(const i32x4*)&Bs[(wc * 128 + j * 16 + lr) * 32 + g * 8];
#pragma unroll
        for (int i = 0; i < 4; ++i)
#pragma unroll
            for (int j = 0; j < 8; ++j) mfma16(acc[i][j], a[i], b[j]);
    }
    asm volatile("s_nop 7\n s_nop 7\n s_nop 7\n s_nop 7");

    const float one = 1.0f;
#pragma unroll
    for (int i = 0; i < 4; ++i) {
#pragma unroll
        for (int r = 0; r < 4; ++r) {
            int row = m0 + wr * 64 + i * 16 + g * 4 + r;
            float dd = dis[row] * 16.f;      // fp4 pre-scale
#pragma unroll
            for (int jh = 0; jh < 4; ++jh) {
                float x = acc[i][2 * jh][r] * dd;
                float y = acc[i][2 * jh + 1][r] * dd;
                uint32_t p = pk_fp4(x, y, one);
                hn4[(size_t)row * 256 + (n0 >> 1) + wc * 64 + jh * 16 + lr] = (uint8_t)p;
            }
        }
    }
}

// ---------------- aggregation + bias + relu + fused mean-pool accumulation ----------------
// One wave covers a full 256B fp4 row per wave-load (lane l owns bytes 4l..4l+3 = 8 cols).
// Each wave independently owns NPW nodes; srcs broadcast via lane-parallel prefetch + shfl.
#define NPW 2
__device__ __forceinline__ void dec8(float a[8], uint32_t v, float one) {
#pragma unroll
    for (int k = 0; k < 4; ++k) {
        f32x2 f = upk_fp4(v >> (8 * k), one);
        a[2 * k] += f[0];
        a[2 * k + 1] += f[1];
    }
}

__global__ __launch_bounds__(256) void k_agg(const uint8_t* __restrict__ hn4,
                                             const float* __restrict__ dis,
                                             const float* __restrict__ bg,
                                             const int* __restrict__ row_ptr,
                                             const int* __restrict__ srcs,
                                             const int* __restrict__ bv,
                                             float* __restrict__ sums) {
    const int t = threadIdx.x;
    const int w = t >> 6, l = t & 63;
    const int node0 = (blockIdx.x * 4 + w) * NPW;
    const float one = 1.0f;
    int cols[4];
    float bgv[8];
#pragma unroll
    for (int k = 0; k < 4; ++k) {
        int b = 4 * l + k;
        cols[k] = ((b >> 4) << 5) + (b & 15);
        bgv[2 * k] = bg[cols[k]];
        bgv[2 * k + 1] = bg[cols[k] + 16];
    }
    float s[8] = {};
    int curb = bv[node0];
    for (int ni = 0; ni < NPW; ++ni) {
        int node = node0 + ni;
        int b = bv[node];
        if (b != curb) {
#pragma unroll
            for (int k = 0; k < 4; ++k) {
                atomicAdd(&sums[(size_t)curb * PD + cols[k]], s[2 * k]);
                atomicAdd(&sums[(size_t)curb * PD + cols[k] + 16], s[2 * k + 1]);
            }
#pragma unroll
            for (int k = 0; k < 8; ++k) s[k] = 0.f;
            curb = b;
        }
        float a[8] = {};
        int beg = row_ptr[node], end = row_ptr[node + 1];
        for (int base = beg; base < end; base += 64) {
            int nq = end - base;
            if (nq > 64) nq = 64;
            int sv = srcs[(base + l < end) ? (base + l) : (end - 1)];  // lane-parallel prefetch
            int q = 0;
            for (; q + 8 <= nq; q += 8) {
                uint32_t v[8];
#pragma unroll
                for (int j = 0; j < 8; ++j) {
                    int sn = __shfl(sv, q + j);
                    v[j] = *(const uint32_t*)&hn4[(size_t)sn * 256 + l * 4];
                }
#pragma unroll
                for (int j = 0; j < 8; ++j) dec8(a, v[j], one);
            }
            for (; q < nq; ++q) {
                int sn = __shfl(sv, q);
                uint32_t v = *(const uint32_t*)&hn4[(size_t)sn * 256 + l * 4];
                dec8(a, v, one);
            }
        }
        {   // self loop
            uint32_t v = *(const uint32_t*)&hn4[(size_t)node * 256 + l * 4];
            dec8(a, v, one);
        }
        float dd = dis[node] * 0.0625f;   // undo fp4 pre-scale
#pragma unroll
        for (int k = 0; k < 8; ++k) s[k] += fmaxf(fmaf(a[k], dd, bgv[k]), 0.f);
    }
#pragma unroll
    for (int k = 0; k < 4; ++k) {
        atomicAdd(&sums[(size_t)curb * PD + cols[k]], s[2 * k]);
        atomicAdd(&sums[(size_t)curb * PD + cols[k] + 16], s[2 * k + 1]);
    }
}

// ---------------- dense partial core ----------------
__device__ __forceinline__ void lin_part_core(const float* __restrict__ a,
                                              const float* __restrict__ wp,
                                              float* __restrict__ P, int slot, int c0) {
    float acc0 = 0.f, acc1 = 0.f, acc2 = 0.f, acc3 = 0.f;
    float acc4 = 0.f, acc5 = 0.f, acc6 = 0.f, acc7 = 0.f;
#pragma unroll 4
    for (int k = 0; k < 256; k += 8) {
        float a0 = a[k + 0], a1 = a[k + 1], a2 = a[k + 2], a3 = a[k + 3];
        float a4 = a[k + 4], a5 = a[k + 5], a6 = a[k + 6], a7 = a[k + 7];
        float2 w0 = *(const float2*)&wp[(size_t)(k + 0) * PD];
        float2 w1 = *(const float2*)&wp[(size_t)(k + 1) * PD];
        float2 w2 = *(const float2*)&wp[(size_t)(k + 2) * PD];
        float2 w3 = *(const float2*)&wp[(size_t)(k + 3) * PD];
        float2 w4 = *(const float2*)&wp[(size_t)(k + 4) * PD];
        float2 w5 = *(const float2*)&wp[(size_t)(k + 5) * PD];
        float2 w6 = *(const float2*)&wp[(size_t)(k + 6) * PD];
        float2 w7 = *(const float2*)&wp[(size_t)(k + 7) * PD];
        acc0 = fmaf(a0, w0.x, acc0); acc1 = fmaf(a0, w0.y, acc1);
        acc2 = fmaf(a1, w1.x, acc2); acc3 = fmaf(a1, w1.y, acc3);
        acc4 = fmaf(a2, w2.x, acc4); acc5 = fmaf(a2, w2.y, acc5);
        acc6 = fmaf(a3, w3.x, acc6); acc7 = fmaf(a3, w3.y, acc7);
        acc0 = fmaf(a4, w4.x, acc0); acc1 = fmaf(a4, w4.y, acc1);
        acc2 = fmaf(a5, w5.x, acc2); acc3 = fmaf(a5, w5.y, acc3);
        acc4 = fmaf(a6, w6.x, acc4); acc5 = fmaf(a6, w6.y, acc5);
        acc6 = fmaf(a7, w7.x, acc6); acc7 = fmaf(a7, w7.y, acc7);
    }
    P[(size_t)slot * PD + c0] = (acc0 + acc2) + (acc4 + acc6);
    P[(size_t)slot * PD + c0 + 1] = (acc1 + acc3) + (acc5 + acc7);
}

// generic: grid (BATCH, nch); slot = row*8 + kc
__global__ __launch_bounds__(256) void k_lin_part(const float* __restrict__ A,
                                                  const float* __restrict__ W,
                                                  float* __restrict__ P, int K) {
    const int row = blockIdx.x, kc = blockIdx.y, c0 = threadIdx.x * 2;
    lin_part_core(A + (size_t)row * K + kc * 256, W + (size_t)kc * 256 * PD + c0,
                  P, row * 8 + kc, c0);
}

// fused img+txt: grid (BATCH, 6); kc<3 -> img, else txt
__global__ __launch_bounds__(256) void k_lin_part_it(const float* __restrict__ IMG,
                                                     const float* __restrict__ TXT,
                                                     const float* __restrict__ Wi,
                                                     const float* __restrict__ Wt,
                                                     float* __restrict__ P) {
    const int row = blockIdx.x, kc = blockIdx.y, c0 = threadIdx.x * 2;
    const float* A = (kc < 3) ? IMG : TXT;
    const float* W = (kc < 3) ? Wi : Wt;
    const int sub = (kc < 3) ? kc : kc - 3;
    lin_part_core(A + (size_t)row * CLIPD + sub * 256, W + (size_t)sub * 256 * PD + c0,
                  P, row * 8 + kc, c0);
}

// fused reduce for img+txt: grid (BATCH, 2) -> combined[row][side*512 + c]
__global__ __launch_bounds__(256) void k_lin_red_it(const float* __restrict__ P,
                                                    const float* __restrict__ bi,
                                                    const float* __restrict__ bt,
                                                    float* __restrict__ C) {
    const int row = blockIdx.x, side = blockIdx.y, c0 = threadIdx.x * 2;
    const float* p = P + ((size_t)row * 8 + side * 3) * PD + c0;
    float r0 = p[0] + p[PD] + p[2 * PD];
    float r1 = p[1] + p[PD + 1] + p[2 * PD + 1];
    const float* bias = side ? bt : bi;
    C[(size_t)row * 1024 + side * PD + c0] = r0 + bias[c0];
    C[(size_t)row * 1024 + side * PD + c0 + 1] = r1 + bias[c0 + 1];
}

// reduce partials + (mean-scale) + bias + relu, then dot with w2 -> y[row]
__global__ __launch_bounds__(256) void k_reddot(const float* __restrict__ P,
                                                const float* __restrict__ bias,
                                                const float* __restrict__ w2,
                                                const float* __restrict__ b2,
                                                float* __restrict__ y,
                                                int nch, const int* __restrict__ cnts) {
    __shared__ float wred[4];
    const int row = blockIdx.x;
    const int t = threadIdx.x;
    const int c0 = t * 2;
    const float* p = P + (size_t)row * 8 * PD + c0;
    float r0 = p[0], r1 = p[1];
    if (nch > 1) { r0 += p[PD];     r1 += p[PD + 1]; }
    if (nch > 2) { r0 += p[2 * PD]; r1 += p[2 * PD + 1]; }
    if (nch > 3) { r0 += p[3 * PD]; r1 += p[3 * PD + 1]; }
    float s = 1.f;
    if (cnts) s = 1.f / fmaxf((float)cnts[row], 1.f);
    r0 = fmaxf(fmaf(r0, s, bias[c0]), 0.f);
    r1 = fmaxf(fmaf(r1, s, bias[c0 + 1]), 0.f);
    float partial = fmaf(r0, w2[c0], r1 * w2[c0 + 1]);
#pragma unroll
    for (int off = 32; off; off >>= 1) partial += __shfl_down(partial, off);
    if ((t & 63) == 0) wred[t >> 6] = partial;
    __syncthreads();
    if (t == 0) y[row] = (wred[0] + wred[1]) + (wred[2] + wred[3]) + b2[0];
}

// ---------------- logits + BCE loss ----------------
__global__ void k_final(const float* __restrict__ yi, const float* __restrict__ ys,
                        const float* __restrict__ ans, float* __restrict__ out) {
    __shared__ float red[128];
    int t = threadIdx.x;   // 128
    float l = fmaxf(yi[t], ys[t]);
    out[t] = l;
    float li = fmaxf(l, 0.f) + log1pf(expf(-fabsf(l))) - l * ans[t];
    red[t] = li;
    __syncthreads();
    for (int off = 64; off; off >>= 1) {
        if (t < off) red[t] += red[t + off];
        __syncthreads();
    }
    if (t == 0) out[BATCH] = red[0] / (float)BATCH;
}

extern "C" void kernel_launch(void* const* d_in, const int* in_sizes, int n_in,
                              void* d_out, int out_size, void* d_ws, size_t ws_size,
                              hipStream_t stream) {
    const float* image_features = (const float*)d_in[0];
    const float* text_features  = (const float*)d_in[1];
    const float* answer         = (const float*)d_in[2];
    const float* x_nodes        = (const float*)d_in[3];
    const int*   edge_index     = (const int*)d_in[4];
    const int*   batch_vec      = (const int*)d_in[5];
    const float* W_img = (const float*)d_in[6];
    const float* b_img = (const float*)d_in[7];
    const float* W_txt = (const float*)d_in[8];
    const float* b_txt = (const float*)d_in[9];
    const float* W1  = (const float*)d_in[10];
    const float* b1  = (const float*)d_in[11];
    const float* W2  = (const float*)d_in[12];
    const float* b2  = (const float*)d_in[13];
    const float* Wg  = (const float*)d_in[14];
    const float* bg  = (const float*)d_in[15];
    const float* Ws1 = (const float*)d_in[16];
    const float* bs1 = (const float*)d_in[17];
    const float* Ws2 = (const float*)d_in[18];
    const float* bs2 = (const float*)d_in[19];
    float* out = (float*)d_out;

    char* base = (char*)d_ws;
    size_t cur = 0;
    auto alloc = [&](size_t bytes) -> void* {
        void* r = base + cur;
        cur = (cur + bytes + 255) & ~(size_t)255;
        return r;
    };
    unsigned short* WgT = (unsigned short*)alloc((size_t)PD * PD * 2);
    uint8_t* hn4   = (uint8_t*)alloc((size_t)N_NODES * 256);
    int*   deg     = (int*)alloc((size_t)N_NODES * 4);
    float* dis     = (float*)alloc((size_t)N_NODES * 4);
    int*   row_ptr = (int*)alloc((size_t)(N_NODES + 1) * 4);
    int*   fill    = (int*)alloc((size_t)N_NODES * 4);
    int*   srcs    = (int*)alloc((size_t)N_EDGES * 4);
    float* sums    = (float*)alloc((size_t)BATCH * PD * 4);
    int*   cnts    = (int*)alloc((size_t)BATCH * 4);
    float* Ppart   = (float*)alloc((size_t)BATCH * 8 * PD * 4);
    float* combined = (float*)alloc((size_t)BATCH * 1024 * 4);
    float* yi      = (float*)alloc((size_t)BATCH * 4);
    float* ys      = (float*)alloc((size_t)BATCH * 4);

    // zero-init via async memsets (graph-capture-safe); deg counts non-self edges
    hipMemsetAsync(deg, 0, (size_t)N_NODES * 4, stream);
    hipMemsetAsync(fill, 0, (size_t)N_NODES * 4, stream);
    hipMemsetAsync(sums, 0, (size_t)BATCH * PD * 4, stream);

    // symbolic-branch preprocessing
    hipLaunchKernelGGL(k_wgt, dim3(16, 16), dim3(32, 32), 0, stream, Wg, WgT, batch_vec, cnts);
    hipLaunchKernelGGL(k_deg, dim3(4096), dim3(256), 0, stream, edge_index, deg);
    hipLaunchKernelGGL(k_scan, dim3(1), dim3(1024), 0, stream, deg, row_ptr, dis);
    hipLaunchKernelGGL(k_scatter, dim3(4096), dim3(256), 0, stream, edge_index, row_ptr, fill, srcs);
    hipLaunchKernelGGL(k_gemm, dim3(N_NODES / 128, PD / 256), dim3(256), 0, stream,
                       x_nodes, WgT, dis, hn4);
    hipLaunchKernelGGL(k_agg, dim3(N_NODES / (NPW * 4)), dim3(256), 0, stream,
                       hn4, dis, bg, row_ptr, srcs, batch_vec, sums);

    // implicit branch: fused img+txt projections
    hipLaunchKernelGGL(k_lin_part_it, dim3(BATCH, 6), dim3(256), 0, stream,
                       image_features, text_features, W_img, W_txt, Ppart);
    hipLaunchKernelGGL(k_lin_red_it, dim3(BATCH, 2), dim3(256), 0, stream,
                       Ppart, b_img, b_txt, combined);
    // classifier layer 1 (K=1024) + dot fused
    hipLaunchKernelGGL(k_lin_part, dim3(BATCH, 4), dim3(256), 0, stream,
                       combined, W1, Ppart, 1024);
    hipLaunchKernelGGL(k_reddot, dim3(BATCH), dim3(256), 0, stream,
                       Ppart, b1, W2, b2, yi, 4, (const int*)nullptr);

    // symbolic classifier (mean-pool folded via cnts), K=512, + dot fused
    hipLaunchKernelGGL(k_lin_part, dim3(BATCH, 2), dim3(256), 0, stream,
                       sums, Ws1, Ppart, PD);
    hipLaunchKernelGGL(k_reddot, dim3(BATCH), dim3(256), 0, stream,
                       Ppart, bs1, Ws2, bs2, ys, 2, cnts);

    // fuse
    hipLaunchKernelGGL(k_final, dim3(1), dim3(128), 0, stream, yi, ys, answer, out);
}

// Round 13
// 366.780 us; speedup vs baseline: 1.4431x; 1.4431x over previous
//
#include <hip/hip_runtime.h>
#include <stdint.h>

#define N_NODES 65536
#define N_EDGES 1048576
#define BATCH   128
#define PD      512
#define CLIPD   768

typedef __attribute__((ext_vector_type(4))) float f32x4;
typedef __attribute__((ext_vector_type(2))) float f32x2;
typedef __attribute__((ext_vector_type(4))) int   i32x4;

__device__ __forceinline__ unsigned short f2b(float f) {
    uint32_t u = __float_as_uint(f);
    return (unsigned short)((u + 0x7fffu + ((u >> 16) & 1u)) >> 16);
}

// packed f32x2 -> bf16x2 (RNE), 1 VALU op
__device__ __forceinline__ uint32_t pk_bf16(float lo, float hi) {
    uint32_t r;
    asm("v_cvt_pk_bf16_f32 %0, %1, %2" : "=v"(r) : "v"(lo), "v"(hi));
    return r;
}

// fp4 e2m1 pack (2 floats -> byte0) / unpack (byte0 -> 2 floats), scale = 1.0 (identity)
__device__ __forceinline__ uint32_t pk_fp4(float x, float y, float one) {
    uint32_t r = 0;
    asm("v_cvt_scalef32_pk_fp4_f32 %0, %1, %2, %3" : "+v"(r) : "v"(x), "v"(y), "v"(one));
    return r;
}
__device__ __forceinline__ f32x2 upk_fp4(uint32_t b, float one) {
    f32x2 r;
    asm("v_cvt_scalef32_pk_f32_fp4 %0, %1, %2" : "=v"(r) : "v"(b), "v"(one));
    return r;
}

// ---------------- Wg transpose+cast to bf16; batch counts via binary search on sorted bv ----------------
__global__ void k_wgt(const float* __restrict__ Wg, unsigned short* __restrict__ WgT,
                      const int* __restrict__ bv, int* __restrict__ cnts) {
    __shared__ float tile[32][33];
    int kb = blockIdx.x * 32, nb = blockIdx.y * 32;
    int tx = threadIdx.x, ty = threadIdx.y;
    if (kb == 0 && nb == 0) {
        int tid = ty * 32 + tx;
        if (tid < BATCH) {
            int lo = 0, hi = N_NODES;
            while (lo < hi) { int m = (lo + hi) >> 1; if (bv[m] < tid) lo = m + 1; else hi = m; }
            int lo2 = lo, hi2 = N_NODES;
            while (lo2 < hi2) { int m = (lo2 + hi2) >> 1; if (bv[m] < tid + 1) lo2 = m + 1; else hi2 = m; }
            cnts[tid] = lo2 - lo;
        }
    }
    tile[ty][tx] = Wg[(size_t)(kb + ty) * PD + nb + tx];
    __syncthreads();
    WgT[(size_t)(nb + ty) * PD + kb + tx] = f2b(tile[tx][ty]);
}

// ---------------- degree count over dst (deg = #non-self in-edges; zeroed via memset) ----------------
__global__ void k_deg(const int* __restrict__ ei, int* __restrict__ deg) {
    int e = blockIdx.x * 256 + threadIdx.x;   // E threads
    atomicAdd(&deg[ei[N_EDGES + e]], 1);
}

// ---------------- coalesced wave-scan: row_ptr = exclusive scan of deg; dis = rsqrt(deg+1) ----------------
__global__ void k_scan(const int* __restrict__ deg, int* __restrict__ row_ptr,
                       float* __restrict__ dis) {
    __shared__ int wsum[16];
    const int t = threadIdx.x;            // 1024
    const int w = t >> 6, l = t & 63;
    const int base = w * 4096;            // contiguous region per wave
    int s = 0;
    for (int i = 0; i < 64; ++i) s += deg[base + i * 64 + l];
#pragma unroll
    for (int off = 1; off < 64; off <<= 1) s += __shfl_xor(s, off);
    if (l == 0) wsum[w] = s;
    __syncthreads();
    int carry = 0;
    for (int i = 0; i < 16; ++i) carry += (i < w) ? wsum[i] : 0;
    int idx = base + l;
    int d = deg[idx];
    for (int i = 0; i < 64; ++i) {
        int dn = 0;
        if (i < 63) dn = deg[idx + 64];
        int v = d;
        int inc = v;
#pragma unroll
        for (int off = 1; off < 64; off <<= 1) {
            int n = __shfl_up(inc, off);
            if (l >= off) inc += n;
        }
        row_ptr[idx] = carry + inc - v;
        dis[idx] = rsqrtf((float)(d + 1));
        carry += __shfl(inc, 63);
        idx += 64;
        d = dn;
    }
    if (t == 1023) row_ptr[N_NODES] = carry;  // == E
}

// ---------------- scatter edges into CSR buckets ----------------
__global__ void k_scatter(const int* __restrict__ ei, const int* __restrict__ row_ptr,
                          int* __restrict__ fill, int* __restrict__ srcs) {
    int e = blockIdx.x * 256 + threadIdx.x;
    int d = ei[N_EDGES + e];
    int pos = row_ptr[d] + atomicAdd(&fill[d], 1);
    srcs[pos] = ei[e];
}

// ---------------- big GEMM: hn4 = fp4( 16 * dis[i] * (x[i] @ Wg) ) ----------------
// 128x256 tile, BK=32, 4 waves. fp4 row (256B): byte b holds cols ((b>>4)*32+(b&15), +16).
__device__ __forceinline__ void mfma16(f32x4& acc, i32x4 a, i32x4 b) {
    asm("v_mfma_f32_16x16x32_bf16 %0, %1, %2, %0" : "+v"(acc) : "v"(a), "v"(b));
}

__global__ __launch_bounds__(256) void k_gemm(const float* __restrict__ X,
                                              const unsigned short* __restrict__ WgT,
                                              const float* __restrict__ dis,
                                              uint8_t* __restrict__ hn4) {
    __shared__ __align__(16) unsigned short As[128 * 32];
    __shared__ __align__(16) unsigned short Bs[256 * 32];
    const int m0 = blockIdx.x * 128;
    const int n0 = blockIdx.y * 256;
    const int t = threadIdx.x;
    const int lane = t & 63, w = t >> 6;
    const int wr = w >> 1, wc = w & 1;       // wave tile: 64 rows x 128 cols
    const int g = lane >> 4, lr = lane & 15;

    f32x4 acc[4][8] = {};

    for (int k0 = 0; k0 < PD; k0 += 32) {
        __syncthreads();
#pragma unroll
        for (int it = 0; it < 4; ++it) {
            int idx = it * 256 + t;
            int r = idx >> 3, kc = (idx & 7) * 4;
            float4 v = *(const float4*)&X[(size_t)(m0 + r) * PD + k0 + kc];
            uint2 o;
            o.x = pk_bf16(v.x, v.y);
            o.y = pk_bf16(v.z, v.w);
            *(uint2*)&As[r * 32 + kc] = o;
        }
#pragma unroll
        for (int it = 0; it < 4; ++it) {
            int idx = it * 256 + t;
            int r = idx >> 2, kc = (idx & 3) * 8;
            *(uint4*)&Bs[r * 32 + kc] = *(const uint4*)&WgT[(size_t)(n0 + r) * PD + k0 + kc];
        }
        __syncthreads();

        i32x4 a[4], b[8];
#pragma unroll
        for (int i = 0; i < 4; ++i) a[i] = *(const i32x4*)&As[(wr * 64 + i * 16 + lr) * 32 + g * 8];
#pragma unroll
        for (int j = 0; j < 8; ++j) b[j] = *(const i32x4*)&Bs[(wc * 128 + j * 16 + lr) * 32 + g * 8];
#pragma unroll
        for (int i = 0; i < 4; ++i)
#pragma unroll
            for (int j = 0; j < 8; ++j) mfma16(acc[i][j], a[i], b[j]);
    }
    asm volatile("s_nop 7\n s_nop 7\n s_nop 7\n s_nop 7");

    const float one = 1.0f;
#pragma unroll
    for (int i = 0; i < 4; ++i) {
#pragma unroll
        for (int r = 0; r < 4; ++r) {
            int row = m0 + wr * 64 + i * 16 + g * 4 + r;
            float dd = dis[row] * 16.f;      // fp4 pre-scale
#pragma unroll
            for (int jh = 0; jh < 4; ++jh) {
                float x = acc[i][2 * jh][r] * dd;
                float y = acc[i][2 * jh + 1][r] * dd;
                uint32_t p = pk_fp4(x, y, one);
                hn4[(size_t)row * 256 + (n0 >> 1) + wc * 64 + jh * 16 + lr] = (uint8_t)p;
            }
        }
    }
}

// ---------------- aggregation + bias + relu + fused mean-pool accumulation ----------------
// r10 structure (measured best): 256 threads; thread t owns byte t of each 256B fp4 row
// -> cols c0=(t>>4)*32+(t&15), c1=c0+16.  NPB=8, 16-deep load pipeline.
#define NPB 8
__global__ __launch_bounds__(256) void k_agg(const uint8_t* __restrict__ hn4,
                                             const float* __restrict__ dis,
                                             const float* __restrict__ bg,
                                             const int* __restrict__ row_ptr,
                                             const int* __restrict__ srcs,
                                             const int* __restrict__ bv,
                                             float* __restrict__ sums) {
    const int t = threadIdx.x;
    const int c0 = (t >> 4) * 32 + (t & 15);
    const int c1 = c0 + 16;
    const int node0 = blockIdx.x * NPB;
    const float bg0 = bg[c0], bg1 = bg[c1];
    const float one = 1.0f;
    float s0 = 0.f, s1 = 0.f;
    int curb = bv[node0];
    for (int ni = 0; ni < NPB; ++ni) {
        int node = node0 + ni;
        int b = bv[node];
        if (b != curb) {
            atomicAdd(&sums[(size_t)curb * PD + c0], s0);
            atomicAdd(&sums[(size_t)curb * PD + c1], s1);
            s0 = s1 = 0.f;
            curb = b;
        }
        float a0 = 0.f, a1 = 0.f;
        int beg = row_ptr[node], end = row_ptr[node + 1];
        int e = beg;
        for (; e + 16 <= end; e += 16) {
            int sn[16];
#pragma unroll
            for (int q = 0; q < 16; ++q) sn[q] = srcs[e + q];
            uint32_t v[16];
#pragma unroll
            for (int q = 0; q < 16; ++q)
                v[q] = hn4[(size_t)sn[q] * 256 + t];
#pragma unroll
            for (int q = 0; q < 16; ++q) {
                f32x2 f = upk_fp4(v[q], one);
                a0 += f[0];
                a1 += f[1];
            }
        }
        for (; e + 8 <= end; e += 8) {
            int sn[8];
#pragma unroll
            for (int q = 0; q < 8; ++q) sn[q] = srcs[e + q];
            uint32_t v[8];
#pragma unroll
            for (int q = 0; q < 8; ++q)
                v[q] = hn4[(size_t)sn[q] * 256 + t];
#pragma unroll
            for (int q = 0; q < 8; ++q) {
                f32x2 f = upk_fp4(v[q], one);
                a0 += f[0];
                a1 += f[1];
            }
        }
        for (; e < end; ++e) {
            f32x2 f = upk_fp4(hn4[(size_t)srcs[e] * 256 + t], one);
            a0 += f[0];
            a1 += f[1];
        }
        {   // self loop
            f32x2 f = upk_fp4(hn4[(size_t)node * 256 + t], one);
            a0 += f[0];
            a1 += f[1];
        }
        float dd = dis[node] * 0.0625f;   // undo fp4 pre-scale
        a0 = fmaxf(fmaf(a0, dd, bg0), 0.f);
        a1 = fmaxf(fmaf(a1, dd, bg1), 0.f);
        s0 += a0;
        s1 += a1;
    }
    atomicAdd(&sums[(size_t)curb * PD + c0], s0);
    atomicAdd(&sums[(size_t)curb * PD + c1], s1);
}

// ---------------- dense partial core ----------------
__device__ __forceinline__ void lin_part_core(const float* __restrict__ a,
                                              const float* __restrict__ wp,
                                              float* __restrict__ P, int slot, int c0) {
    float acc0 = 0.f, acc1 = 0.f, acc2 = 0.f, acc3 = 0.f;
    float acc4 = 0.f, acc5 = 0.f, acc6 = 0.f, acc7 = 0.f;
#pragma unroll 4
    for (int k = 0; k < 256; k += 8) {
        float a0 = a[k + 0], a1 = a[k + 1], a2 = a[k + 2], a3 = a[k + 3];
        float a4 = a[k + 4], a5 = a[k + 5], a6 = a[k + 6], a7 = a[k + 7];
        float2 w0 = *(const float2*)&wp[(size_t)(k + 0) * PD];
        float2 w1 = *(const float2*)&wp[(size_t)(k + 1) * PD];
        float2 w2 = *(const float2*)&wp[(size_t)(k + 2) * PD];
        float2 w3 = *(const float2*)&wp[(size_t)(k + 3) * PD];
        float2 w4 = *(const float2*)&wp[(size_t)(k + 4) * PD];
        float2 w5 = *(const float2*)&wp[(size_t)(k + 5) * PD];
        float2 w6 = *(const float2*)&wp[(size_t)(k + 6) * PD];
        float2 w7 = *(const float2*)&wp[(size_t)(k + 7) * PD];
        acc0 = fmaf(a0, w0.x, acc0); acc1 = fmaf(a0, w0.y, acc1);
        acc2 = fmaf(a1, w1.x, acc2); acc3 = fmaf(a1, w1.y, acc3);
        acc4 = fmaf(a2, w2.x, acc4); acc5 = fmaf(a2, w2.y, acc5);
        acc6 = fmaf(a3, w3.x, acc6); acc7 = fmaf(a3, w3.y, acc7);
        acc0 = fmaf(a4, w4.x, acc0); acc1 = fmaf(a4, w4.y, acc1);
        acc2 = fmaf(a5, w5.x, acc2); acc3 = fmaf(a5, w5.y, acc3);
        acc4 = fmaf(a6, w6.x, acc4); acc5 = fmaf(a6, w6.y, acc5);
        acc6 = fmaf(a7, w7.x, acc6); acc7 = fmaf(a7, w7.y, acc7);
    }
    P[(size_t)slot * PD + c0] = (acc0 + acc2) + (acc4 + acc6);
    P[(size_t)slot * PD + c0 + 1] = (acc1 + acc3) + (acc5 + acc7);
}

// generic: grid (BATCH, nch); slot = row*8 + kc
__global__ __launch_bounds__(256) void k_lin_part(const float* __restrict__ A,
                                                  const float* __restrict__ W,
                                                  float* __restrict__ P, int K) {
    const int row = blockIdx.x, kc = blockIdx.y, c0 = threadIdx.x * 2;
    lin_part_core(A + (size_t)row * K + kc * 256, W + (size_t)kc * 256 * PD + c0,
                  P, row * 8 + kc, c0);
}

// fused img+txt: grid (BATCH, 6); kc<3 -> img, else txt
__global__ __launch_bounds__(256) void k_lin_part_it(const float* __restrict__ IMG,
                                                     const float* __restrict__ TXT,
                                                     const float* __restrict__ Wi,
                                                     const float* __restrict__ Wt,
                                                     float* __restrict__ P) {
    const int row = blockIdx.x, kc = blockIdx.y, c0 = threadIdx.x * 2;
    const float* A = (kc < 3) ? IMG : TXT;
    const float* W = (kc < 3) ? Wi : Wt;
    const int sub = (kc < 3) ? kc : kc - 3;
    lin_part_core(A + (size_t)row * CLIPD + sub * 256, W + (size_t)sub * 256 * PD + c0,
                  P, row * 8 + kc, c0);
}

// fused reduce for img+txt: grid (BATCH, 2) -> combined[row][side*512 + c]
__global__ __launch_bounds__(256) void k_lin_red_it(const float* __restrict__ P,
                                                    const float* __restrict__ bi,
                                                    const float* __restrict__ bt,
                                                    float* __restrict__ C) {
    const int row = blockIdx.x, side = blockIdx.y, c0 = threadIdx.x * 2;
    const float* p = P + ((size_t)row * 8 + side * 3) * PD + c0;
    float r0 = p[0] + p[PD] + p[2 * PD];
    float r1 = p[1] + p[PD + 1] + p[2 * PD + 1];
    const float* bias = side ? bt : bi;
    C[(size_t)row * 1024 + side * PD + c0] = r0 + bias[c0];
    C[(size_t)row * 1024 + side * PD + c0 + 1] = r1 + bias[c0 + 1];
}

// reduce partials + (mean-scale) + bias + relu, then dot with w2 -> y[row]
__global__ __launch_bounds__(256) void k_reddot(const float* __restrict__ P,
                                                const float* __restrict__ bias,
                                                const float* __restrict__ w2,
                                                const float* __restrict__ b2,
                                                float* __restrict__ y,
                                                int nch, const int* __restrict__ cnts) {
    __shared__ float wred[4];
    const int row = blockIdx.x;
    const int t = threadIdx.x;
    const int c0 = t * 2;
    const float* p = P + (size_t)row * 8 * PD + c0;
    float r0 = p[0], r1 = p[1];
    if (nch > 1) { r0 += p[PD];     r1 += p[PD + 1]; }
    if (nch > 2) { r0 += p[2 * PD]; r1 += p[2 * PD + 1]; }
    if (nch > 3) { r0 += p[3 * PD]; r1 += p[3 * PD + 1]; }
    float s = 1.f;
    if (cnts) s = 1.f / fmaxf((float)cnts[row], 1.f);
    r0 = fmaxf(fmaf(r0, s, bias[c0]), 0.f);
    r1 = fmaxf(fmaf(r1, s, bias[c0 + 1]), 0.f);
    float partial = fmaf(r0, w2[c0], r1 * w2[c0 + 1]);
#pragma unroll
    for (int off = 32; off; off >>= 1) partial += __shfl_down(partial, off);
    if ((t & 63) == 0) wred[t >> 6] = partial;
    __syncthreads();
    if (t == 0) y[row] = (wred[0] + wred[1]) + (wred[2] + wred[3]) + b2[0];
}

// ---------------- logits + BCE loss ----------------
__global__ void k_final(const float* __restrict__ yi, const float* __restrict__ ys,
                        const float* __restrict__ ans, float* __restrict__ out) {
    __shared__ float red[128];
    int t = threadIdx.x;   // 128
    float l = fmaxf(yi[t], ys[t]);
    out[t] = l;
    float li = fmaxf(l, 0.f) + log1pf(expf(-fabsf(l))) - l * ans[t];
    red[t] = li;
    __syncthreads();
    for (int off = 64; off; off >>= 1) {
        if (t < off) red[t] += red[t + off];
        __syncthreads();
    }
    if (t == 0) out[BATCH] = red[0] / (float)BATCH;
}

extern "C" void kernel_launch(void* const* d_in, const int* in_sizes, int n_in,
                              void* d_out, int out_size, void* d_ws, size_t ws_size,
                              hipStream_t stream) {
    const float* image_features = (const float*)d_in[0];
    const float* text_features  = (const float*)d_in[1];
    const float* answer         = (const float*)d_in[2];
    const float* x_nodes        = (const float*)d_in[3];
    const int*   edge_index     = (const int*)d_in[4];
    const int*   batch_vec      = (const int*)d_in[5];
    const float* W_img = (const float*)d_in[6];
    const float* b_img = (const float*)d_in[7];
    const float* W_txt = (const float*)d_in[8];
    const float* b_txt = (const float*)d_in[9];
    const float* W1  = (const float*)d_in[10];
    const float* b1  = (const float*)d_in[11];
    const float* W2  = (const float*)d_in[12];
    const float* b2  = (const float*)d_in[13];
    const float* Wg  = (const float*)d_in[14];
    const float* bg  = (const float*)d_in[15];
    const float* Ws1 = (const float*)d_in[16];
    const float* bs1 = (const float*)d_in[17];
    const float* Ws2 = (const float*)d_in[18];
    const float* bs2 = (const float*)d_in[19];
    float* out = (float*)d_out;

    char* base = (char*)d_ws;
    size_t cur = 0;
    auto alloc = [&](size_t bytes) -> void* {
        void* r = base + cur;
        cur = (cur + bytes + 255) & ~(size_t)255;
        return r;
    };
    unsigned short* WgT = (unsigned short*)alloc((size_t)PD * PD * 2);
    uint8_t* hn4   = (uint8_t*)alloc((size_t)N_NODES * 256);
    int*   deg     = (int*)alloc((size_t)N_NODES * 4);
    float* dis     = (float*)alloc((size_t)N_NODES * 4);
    int*   row_ptr = (int*)alloc((size_t)(N_NODES + 1) * 4);
    int*   fill    = (int*)alloc((size_t)N_NODES * 4);
    int*   srcs    = (int*)alloc((size_t)N_EDGES * 4);
    float* sums    = (float*)alloc((size_t)BATCH * PD * 4);
    int*   cnts    = (int*)alloc((size_t)BATCH * 4);
    float* Ppart   = (float*)alloc((size_t)BATCH * 8 * PD * 4);
    float* combined = (float*)alloc((size_t)BATCH * 1024 * 4);
    float* yi      = (float*)alloc((size_t)BATCH * 4);
    float* ys      = (float*)alloc((size_t)BATCH * 4);

    // zero-init via async memsets (graph-capture-safe); deg counts non-self edges
    hipMemsetAsync(deg, 0, (size_t)N_NODES * 4, stream);
    hipMemsetAsync(fill, 0, (size_t)N_NODES * 4, stream);
    hipMemsetAsync(sums, 0, (size_t)BATCH * PD * 4, stream);

    // symbolic-branch preprocessing
    hipLaunchKernelGGL(k_wgt, dim3(16, 16), dim3(32, 32), 0, stream, Wg, WgT, batch_vec, cnts);
    hipLaunchKernelGGL(k_deg, dim3(4096), dim3(256), 0, stream, edge_index, deg);
    hipLaunchKernelGGL(k_scan, dim3(1), dim3(1024), 0, stream, deg, row_ptr, dis);
    hipLaunchKernelGGL(k_scatter, dim3(4096), dim3(256), 0, stream, edge_index, row_ptr, fill, srcs);
    hipLaunchKernelGGL(k_gemm, dim3(N_NODES / 128, PD / 256), dim3(256), 0, stream,
                       x_nodes, WgT, dis, hn4);
    hipLaunchKernelGGL(k_agg, dim3(N_NODES / NPB), dim3(256), 0, stream,
                       hn4, dis, bg, row_ptr, srcs, batch_vec, sums);

    // implicit branch: fused img+txt projections
    hipLaunchKernelGGL(k_lin_part_it, dim3(BATCH, 6), dim3(256), 0, stream,
                       image_features, text_features, W_img, W_txt, Ppart);
    hipLaunchKernelGGL(k_lin_red_it, dim3(BATCH, 2), dim3(256), 0, stream,
                       Ppart, b_img, b_txt, combined);
    // classifier layer 1 (K=1024) + dot fused
    hipLaunchKernelGGL(k_lin_part, dim3(BATCH, 4), dim3(256), 0, stream,
                       combined, W1, Ppart, 1024);
    hipLaunchKernelGGL(k_reddot, dim3(BATCH), dim3(256), 0, stream,
                       Ppart, b1, W2, b2, yi, 4, (const int*)nullptr);

    // symbolic classifier (mean-pool folded via cnts), K=512, + dot fused
    hipLaunchKernelGGL(k_lin_part, dim3(BATCH, 2), dim3(256), 0, stream,
                       sums, Ws1, Ppart, PD);
    hipLaunchKernelGGL(k_reddot, dim3(BATCH), dim3(256), 0, stream,
                       Ppart, bs1, Ws2, bs2, ys, 2, cnts);

    // fuse
    hipLaunchKernelGGL(k_final, dim3(1), dim3(128), 0, stream, yi, ys, answer, out);
}

// Round 14
// 359.708 us; speedup vs baseline: 1.4714x; 1.0197x over previous
//
#include <hip/hip_runtime.h>
#include <stdint.h>

#define N_NODES 65536
#define N_EDGES 1048576
#define BATCH   128
#define PD      512
#define CLIPD   768

typedef __attribute__((ext_vector_type(4))) float f32x4;
typedef __attribute__((ext_vector_type(2))) float f32x2;
typedef __attribute__((ext_vector_type(4))) int   i32x4;

__device__ __forceinline__ unsigned short f2b(float f) {
    uint32_t u = __float_as_uint(f);
    return (unsigned short)((u + 0x7fffu + ((u >> 16) & 1u)) >> 16);
}

// packed f32x2 -> bf16x2 (RNE), 1 VALU op
__device__ __forceinline__ uint32_t pk_bf16(float lo, float hi) {
    uint32_t r;
    asm("v_cvt_pk_bf16_f32 %0, %1, %2" : "=v"(r) : "v"(lo), "v"(hi));
    return r;
}

// fp4 e2m1 pack (2 floats -> byte0) / unpack (byte0 -> 2 floats), scale = 1.0 (identity)
__device__ __forceinline__ uint32_t pk_fp4(float x, float y, float one) {
    uint32_t r = 0;
    asm("v_cvt_scalef32_pk_fp4_f32 %0, %1, %2, %3" : "+v"(r) : "v"(x), "v"(y), "v"(one));
    return r;
}
__device__ __forceinline__ f32x2 upk_fp4(uint32_t b, float one) {
    f32x2 r;
    asm("v_cvt_scalef32_pk_f32_fp4 %0, %1, %2" : "=v"(r) : "v"(b), "v"(one));
    return r;
}

// async global->LDS, 16B per lane (dest must be wave-uniform base + lane*16)
__device__ __forceinline__ void gl_lds16(const unsigned short* g, unsigned short* l) {
    __builtin_amdgcn_global_load_lds((const __attribute__((address_space(1))) void*)g,
                                     (__attribute__((address_space(3))) void*)l, 16, 0, 0);
}

// ---------------- Wg transpose+cast to bf16; batch counts via binary search on sorted bv ----------------
__global__ void k_wgt(const float* __restrict__ Wg, unsigned short* __restrict__ WgT,
                      const int* __restrict__ bv, int* __restrict__ cnts) {
    __shared__ float tile[32][33];
    int kb = blockIdx.x * 32, nb = blockIdx.y * 32;
    int tx = threadIdx.x, ty = threadIdx.y;
    if (kb == 0 && nb == 0) {
        int tid = ty * 32 + tx;
        if (tid < BATCH) {
            int lo = 0, hi = N_NODES;
            while (lo < hi) { int m = (lo + hi) >> 1; if (bv[m] < tid) lo = m + 1; else hi = m; }
            int lo2 = lo, hi2 = N_NODES;
            while (lo2 < hi2) { int m = (lo2 + hi2) >> 1; if (bv[m] < tid + 1) lo2 = m + 1; else hi2 = m; }
            cnts[tid] = lo2 - lo;
        }
    }
    tile[ty][tx] = Wg[(size_t)(kb + ty) * PD + nb + tx];
    __syncthreads();
    WgT[(size_t)(nb + ty) * PD + kb + tx] = f2b(tile[tx][ty]);
}

// ---------------- degree count over dst (deg = #non-self in-edges; zeroed via memset) ----------------
__global__ void k_deg(const int* __restrict__ ei, int* __restrict__ deg) {
    int e = blockIdx.x * 256 + threadIdx.x;   // E threads
    atomicAdd(&deg[ei[N_EDGES + e]], 1);
}

// ---------------- coalesced wave-scan: row_ptr = exclusive scan of deg; dis = rsqrt(deg+1) ----------------
__global__ void k_scan(const int* __restrict__ deg, int* __restrict__ row_ptr,
                       float* __restrict__ dis) {
    __shared__ int wsum[16];
    const int t = threadIdx.x;            // 1024
    const int w = t >> 6, l = t & 63;
    const int base = w * 4096;            // contiguous region per wave
    int s = 0;
    for (int i = 0; i < 64; ++i) s += deg[base + i * 64 + l];
#pragma unroll
    for (int off = 1; off < 64; off <<= 1) s += __shfl_xor(s, off);
    if (l == 0) wsum[w] = s;
    __syncthreads();
    int carry = 0;
    for (int i = 0; i < 16; ++i) carry += (i < w) ? wsum[i] : 0;
    int idx = base + l;
    int d = deg[idx];
    for (int i = 0; i < 64; ++i) {
        int dn = 0;
        if (i < 63) dn = deg[idx + 64];
        int v = d;
        int inc = v;
#pragma unroll
        for (int off = 1; off < 64; off <<= 1) {
            int n = __shfl_up(inc, off);
            if (l >= off) inc += n;
        }
        row_ptr[idx] = carry + inc - v;
        dis[idx] = rsqrtf((float)(d + 1));
        carry += __shfl(inc, 63);
        idx += 64;
        d = dn;
    }
    if (t == 1023) row_ptr[N_NODES] = carry;  // == E
}

// ---------------- scatter edges into CSR buckets ----------------
__global__ void k_scatter(const int* __restrict__ ei, const int* __restrict__ row_ptr,
                          int* __restrict__ fill, int* __restrict__ srcs) {
    int e = blockIdx.x * 256 + threadIdx.x;
    int d = ei[N_EDGES + e];
    int pos = row_ptr[d] + atomicAdd(&fill[d], 1);
    srcs[pos] = ei[e];
}

// ---------------- big GEMM: hn4 = fp4( 16 * dis[i] * (x[i] @ Wg) ) ----------------
// 128x256 tile, BK=32, 4 waves. XCD-swizzled grid (nwg=1024, bijective). B staged via gl_lds.
// fp4 row (256B): byte b holds cols ((b>>4)*32+(b&15), +16).
__device__ __forceinline__ void mfma16(f32x4& acc, i32x4 a, i32x4 b) {
    asm("v_mfma_f32_16x16x32_bf16 %0, %1, %2, %0" : "+v"(acc) : "v"(a), "v"(b));
}

__global__ __launch_bounds__(256) void k_gemm(const float* __restrict__ X,
                                              const unsigned short* __restrict__ WgT,
                                              const float* __restrict__ dis,
                                              uint8_t* __restrict__ hn4) {
    __shared__ __align__(16) unsigned short As[128 * 32];
    __shared__ __align__(16) unsigned short Bs[256 * 32];
    // XCD-aware swizzle: (m,0) and (m,1) land on the same XCD -> X panel L2 reuse
    const int lin = blockIdx.x + blockIdx.y * 512;     // nwg = 1024
    const int swz = (lin & 7) * 128 + (lin >> 3);
    const int m0 = (swz & 511) * 128;
    const int n0 = (swz >> 9) * 256;
    const int t = threadIdx.x;
    const int lane = t & 63, w = t >> 6;
    const int wr = w >> 1, wc = w & 1;       // wave tile: 64 rows x 128 cols
    const int g = lane >> 4, lr = lane & 15;

    f32x4 acc[4][8] = {};

    for (int k0 = 0; k0 < PD; k0 += 32) {
        __syncthreads();
        // stage A: 128x32 f32 -> bf16 (reg-staged, packed cvt)
#pragma unroll
        for (int it = 0; it < 4; ++it) {
            int idx = it * 256 + t;
            int r = idx >> 3, kc = (idx & 7) * 4;
            float4 v = *(const float4*)&X[(size_t)(m0 + r) * PD + k0 + kc];
            uint2 o;
            o.x = pk_bf16(v.x, v.y);
            o.y = pk_bf16(v.z, v.w);
            *(uint2*)&As[r * 32 + kc] = o;
        }
        // stage B: 256x32 bf16 via async global->LDS (dest = base + lane*16)
#pragma unroll
        for (int it = 0; it < 4; ++it) {
            int idx = it * 256 + t;
            int r = idx >> 2, kc = (idx & 3) * 8;
            gl_lds16(&WgT[(size_t)(n0 + r) * PD + k0 + kc], &Bs[idx * 8]);
        }
        __syncthreads();   // drains vmcnt (incl. gl_lds) + lgkmcnt

        i32x4 a[4], b[8];
#pragma unroll
        for (int i = 0; i < 4; ++i) a[i] = *(const i32x4*)&As[(wr * 64 + i * 16 + lr) * 32 + g * 8];
#pragma unroll
        for (int j = 0; j < 8; ++j) b[j] = *(const i32x4*)&Bs[(wc * 128 + j * 16 + lr) * 32 + g * 8];
#pragma unroll
        for (int i = 0; i < 4; ++i)
#pragma unroll
            for (int j = 0; j < 8; ++j) mfma16(acc[i][j], a[i], b[j]);
    }
    asm volatile("s_nop 7\n s_nop 7\n s_nop 7\n s_nop 7");

    const float one = 1.0f;
#pragma unroll
    for (int i = 0; i < 4; ++i) {
#pragma unroll
        for (int r = 0; r < 4; ++r) {
            int row = m0 + wr * 64 + i * 16 + g * 4 + r;
            float dd = dis[row] * 16.f;      // fp4 pre-scale
#pragma unroll
            for (int jh = 0; jh < 4; ++jh) {
                float x = acc[i][2 * jh][r] * dd;
                float y = acc[i][2 * jh + 1][r] * dd;
                uint32_t p = pk_fp4(x, y, one);
                hn4[(size_t)row * 256 + (n0 >> 1) + wc * 64 + jh * 16 + lr] = (uint8_t)p;
            }
        }
    }
}

// ---------------- aggregation + bias + relu + fused mean-pool accumulation ----------------
// r10 structure (measured best): 256 threads; thread t owns byte t of each 256B fp4 row
// -> cols c0=(t>>4)*32+(t&15), c1=c0+16.  NPB=8; 16-deep gathers + srcs-group prefetch.
#define NPB 8
__global__ __launch_bounds__(256) void k_agg(const uint8_t* __restrict__ hn4,
                                             const float* __restrict__ dis,
                                             const float* __restrict__ bg,
                                             const int* __restrict__ row_ptr,
                                             const int* __restrict__ srcs,
                                             const int* __restrict__ bv,
                                             float* __restrict__ sums) {
    const int t = threadIdx.x;
    const int c0 = (t >> 4) * 32 + (t & 15);
    const int c1 = c0 + 16;
    const int node0 = blockIdx.x * NPB;
    const float bg0 = bg[c0], bg1 = bg[c1];
    const float one = 1.0f;
    float s0 = 0.f, s1 = 0.f;
    int curb = bv[node0];
    for (int ni = 0; ni < NPB; ++ni) {
        int node = node0 + ni;
        int b = bv[node];
        if (b != curb) {
            atomicAdd(&sums[(size_t)curb * PD + c0], s0);
            atomicAdd(&sums[(size_t)curb * PD + c1], s1);
            s0 = s1 = 0.f;
            curb = b;
        }
        float a0 = 0.f, a1 = 0.f;
        int beg = row_ptr[node], end = row_ptr[node + 1];
        int e = beg;
        if (e + 16 <= end) {
            int sn[16];
#pragma unroll
            for (int q = 0; q < 16; ++q) sn[q] = srcs[e + q];
            // pipelined: prefetch next group's indices while gathering current
            for (; e + 32 <= end; e += 16) {
                int sn2[16];
#pragma unroll
                for (int q = 0; q < 16; ++q) sn2[q] = srcs[e + 16 + q];
                uint32_t v[16];
#pragma unroll
                for (int q = 0; q < 16; ++q) v[q] = hn4[(size_t)sn[q] * 256 + t];
#pragma unroll
                for (int q = 0; q < 16; ++q) {
                    f32x2 f = upk_fp4(v[q], one);
                    a0 += f[0];
                    a1 += f[1];
                }
#pragma unroll
                for (int q = 0; q < 16; ++q) sn[q] = sn2[q];
            }
            {   // drain the preloaded group
                uint32_t v[16];
#pragma unroll
                for (int q = 0; q < 16; ++q) v[q] = hn4[(size_t)sn[q] * 256 + t];
#pragma unroll
                for (int q = 0; q < 16; ++q) {
                    f32x2 f = upk_fp4(v[q], one);
                    a0 += f[0];
                    a1 += f[1];
                }
                e += 16;
            }
        }
        for (; e + 8 <= end; e += 8) {
            int sn[8];
#pragma unroll
            for (int q = 0; q < 8; ++q) sn[q] = srcs[e + q];
            uint32_t v[8];
#pragma unroll
            for (int q = 0; q < 8; ++q)
                v[q] = hn4[(size_t)sn[q] * 256 + t];
#pragma unroll
            for (int q = 0; q < 8; ++q) {
                f32x2 f = upk_fp4(v[q], one);
                a0 += f[0];
                a1 += f[1];
            }
        }
        for (; e < end; ++e) {
            f32x2 f = upk_fp4(hn4[(size_t)srcs[e] * 256 + t], one);
            a0 += f[0];
            a1 += f[1];
        }
        {   // self loop
            f32x2 f = upk_fp4(hn4[(size_t)node * 256 + t], one);
            a0 += f[0];
            a1 += f[1];
        }
        float dd = dis[node] * 0.0625f;   // undo fp4 pre-scale
        a0 = fmaxf(fmaf(a0, dd, bg0), 0.f);
        a1 = fmaxf(fmaf(a1, dd, bg1), 0.f);
        s0 += a0;
        s1 += a1;
    }
    atomicAdd(&sums[(size_t)curb * PD + c0], s0);
    atomicAdd(&sums[(size_t)curb * PD + c1], s1);
}

// ---------------- dense partial core ----------------
__device__ __forceinline__ void lin_part_core(const float* __restrict__ a,
                                              const float* __restrict__ wp,
                                              float* __restrict__ P, int slot, int c0) {
    float acc0 = 0.f, acc1 = 0.f, acc2 = 0.f, acc3 = 0.f;
    float acc4 = 0.f, acc5 = 0.f, acc6 = 0.f, acc7 = 0.f;
#pragma unroll 4
    for (int k = 0; k < 256; k += 8) {
        float a0 = a[k + 0], a1 = a[k + 1], a2 = a[k + 2], a3 = a[k + 3];
        float a4 = a[k + 4], a5 = a[k + 5], a6 = a[k + 6], a7 = a[k + 7];
        float2 w0 = *(const float2*)&wp[(size_t)(k + 0) * PD];
        float2 w1 = *(const float2*)&wp[(size_t)(k + 1) * PD];
        float2 w2 = *(const float2*)&wp[(size_t)(k + 2) * PD];
        float2 w3 = *(const float2*)&wp[(size_t)(k + 3) * PD];
        float2 w4 = *(const float2*)&wp[(size_t)(k + 4) * PD];
        float2 w5 = *(const float2*)&wp[(size_t)(k + 5) * PD];
        float2 w6 = *(const float2*)&wp[(size_t)(k + 6) * PD];
        float2 w7 = *(const float2*)&wp[(size_t)(k + 7) * PD];
        acc0 = fmaf(a0, w0.x, acc0); acc1 = fmaf(a0, w0.y, acc1);
        acc2 = fmaf(a1, w1.x, acc2); acc3 = fmaf(a1, w1.y, acc3);
        acc4 = fmaf(a2, w2.x, acc4); acc5 = fmaf(a2, w2.y, acc5);
        acc6 = fmaf(a3, w3.x, acc6); acc7 = fmaf(a3, w3.y, acc7);
        acc0 = fmaf(a4, w4.x, acc0); acc1 = fmaf(a4, w4.y, acc1);
        acc2 = fmaf(a5, w5.x, acc2); acc3 = fmaf(a5, w5.y, acc3);
        acc4 = fmaf(a6, w6.x, acc4); acc5 = fmaf(a6, w6.y, acc5);
        acc6 = fmaf(a7, w7.x, acc6); acc7 = fmaf(a7, w7.y, acc7);
    }
    P[(size_t)slot * PD + c0] = (acc0 + acc2) + (acc4 + acc6);
    P[(size_t)slot * PD + c0 + 1] = (acc1 + acc3) + (acc5 + acc7);
}

// generic: grid (BATCH, nch); slot = row*8 + kc
__global__ __launch_bounds__(256) void k_lin_part(const float* __restrict__ A,
                                                  const float* __restrict__ W,
                                                  float* __restrict__ P, int K) {
    const int row = blockIdx.x, kc = blockIdx.y, c0 = threadIdx.x * 2;
    lin_part_core(A + (size_t)row * K + kc * 256, W + (size_t)kc * 256 * PD + c0,
                  P, row * 8 + kc, c0);
}

// fused img+txt: grid (BATCH, 6); kc<3 -> img, else txt
__global__ __launch_bounds__(256) void k_lin_part_it(const float* __restrict__ IMG,
                                                     const float* __restrict__ TXT,
                                                     const float* __restrict__ Wi,
                                                     const float* __restrict__ Wt,
                                                     float* __restrict__ P) {
    const int row = blockIdx.x, kc = blockIdx.y, c0 = threadIdx.x * 2;
    const float* A = (kc < 3) ? IMG : TXT;
    const float* W = (kc < 3) ? Wi : Wt;
    const int sub = (kc < 3) ? kc : kc - 3;
    lin_part_core(A + (size_t)row * CLIPD + sub * 256, W + (size_t)sub * 256 * PD + c0,
                  P, row * 8 + kc, c0);
}

// fused reduce for img+txt: grid (BATCH, 2) -> combined[row][side*512 + c]
__global__ __launch_bounds__(256) void k_lin_red_it(const float* __restrict__ P,
                                                    const float* __restrict__ bi,
                                                    const float* __restrict__ bt,
                                                    float* __restrict__ C) {
    const int row = blockIdx.x, side = blockIdx.y, c0 = threadIdx.x * 2;
    const float* p = P + ((size_t)row * 8 + side * 3) * PD + c0;
    float r0 = p[0] + p[PD] + p[2 * PD];
    float r1 = p[1] + p[PD + 1] + p[2 * PD + 1];
    const float* bias = side ? bt : bi;
    C[(size_t)row * 1024 + side * PD + c0] = r0 + bias[c0];
    C[(size_t)row * 1024 + side * PD + c0 + 1] = r1 + bias[c0 + 1];
}

// reduce partials + (mean-scale) + bias + relu, then dot with w2 -> y[row]
__global__ __launch_bounds__(256) void k_reddot(const float* __restrict__ P,
                                                const float* __restrict__ bias,
                                                const float* __restrict__ w2,
                                                const float* __restrict__ b2,
                                                float* __restrict__ y,
                                                int nch, const int* __restrict__ cnts) {
    __shared__ float wred[4];
    const int row = blockIdx.x;
    const int t = threadIdx.x;
    const int c0 = t * 2;
    const float* p = P + (size_t)row * 8 * PD + c0;
    float r0 = p[0], r1 = p[1];
    if (nch > 1) { r0 += p[PD];     r1 += p[PD + 1]; }
    if (nch > 2) { r0 += p[2 * PD]; r1 += p[2 * PD + 1]; }
    if (nch > 3) { r0 += p[3 * PD]; r1 += p[3 * PD + 1]; }
    float s = 1.f;
    if (cnts) s = 1.f / fmaxf((float)cnts[row], 1.f);
    r0 = fmaxf(fmaf(r0, s, bias[c0]), 0.f);
    r1 = fmaxf(fmaf(r1, s, bias[c0 + 1]), 0.f);
    float partial = fmaf(r0, w2[c0], r1 * w2[c0 + 1]);
#pragma unroll
    for (int off = 32; off; off >>= 1) partial += __shfl_down(partial, off);
    if ((t & 63) == 0) wred[t >> 6] = partial;
    __syncthreads();
    if (t == 0) y[row] = (wred[0] + wred[1]) + (wred[2] + wred[3]) + b2[0];
}

// ---------------- logits + BCE loss ----------------
__global__ void k_final(const float* __restrict__ yi, const float* __restrict__ ys,
                        const float* __restrict__ ans, float* __restrict__ out) {
    __shared__ float red[128];
    int t = threadIdx.x;   // 128
    float l = fmaxf(yi[t], ys[t]);
    out[t] = l;
    float li = fmaxf(l, 0.f) + log1pf(expf(-fabsf(l))) - l * ans[t];
    red[t] = li;
    __syncthreads();
    for (int off = 64; off; off >>= 1) {
        if (t < off) red[t] += red[t + off];
        __syncthreads();
    }
    if (t == 0) out[BATCH] = red[0] / (float)BATCH;
}

extern "C" void kernel_launch(void* const* d_in, const int* in_sizes, int n_in,
                              void* d_out, int out_size, void* d_ws, size_t ws_size,
                              hipStream_t stream) {
    const float* image_features = (const float*)d_in[0];
    const float* text_features  = (const float*)d_in[1];
    const float* answer         = (const float*)d_in[2];
    const float* x_nodes        = (const float*)d_in[3];
    const int*   edge_index     = (const int*)d_in[4];
    const int*   batch_vec      = (const int*)d_in[5];
    const float* W_img = (const float*)d_in[6];
    const float* b_img = (const float*)d_in[7];
    const float* W_txt = (const float*)d_in[8];
    const float* b_txt = (const float*)d_in[9];
    const float* W1  = (const float*)d_in[10];
    const float* b1  = (const float*)d_in[11];
    const float* W2  = (const float*)d_in[12];
    const float* b2  = (const float*)d_in[13];
    const float* Wg  = (const float*)d_in[14];
    const float* bg  = (const float*)d_in[15];
    const float* Ws1 = (const float*)d_in[16];
    const float* bs1 = (const float*)d_in[17];
    const float* Ws2 = (const float*)d_in[18];
    const float* bs2 = (const float*)d_in[19];
    float* out = (float*)d_out;

    char* base = (char*)d_ws;
    size_t cur = 0;
    auto alloc = [&](size_t bytes) -> void* {
        void* r = base + cur;
        cur = (cur + bytes + 255) & ~(size_t)255;
        return r;
    };
    unsigned short* WgT = (unsigned short*)alloc((size_t)PD * PD * 2);
    uint8_t* hn4   = (uint8_t*)alloc((size_t)N_NODES * 256);
    int*   deg     = (int*)alloc((size_t)N_NODES * 4);
    float* dis     = (float*)alloc((size_t)N_NODES * 4);
    int*   row_ptr = (int*)alloc((size_t)(N_NODES + 1) * 4);
    int*   fill    = (int*)alloc((size_t)N_NODES * 4);
    int*   srcs    = (int*)alloc((size_t)N_EDGES * 4);
    float* sums    = (float*)alloc((size_t)BATCH * PD * 4);
    int*   cnts    = (int*)alloc((size_t)BATCH * 4);
    float* Ppart   = (float*)alloc((size_t)BATCH * 8 * PD * 4);
    float* combined = (float*)alloc((size_t)BATCH * 1024 * 4);
    float* yi      = (float*)alloc((size_t)BATCH * 4);
    float* ys      = (float*)alloc((size_t)BATCH * 4);

    // zero-init via async memsets (graph-capture-safe); deg counts non-self edges
    hipMemsetAsync(deg, 0, (size_t)N_NODES * 4, stream);
    hipMemsetAsync(fill, 0, (size_t)N_NODES * 4, stream);
    hipMemsetAsync(sums, 0, (size_t)BATCH * PD * 4, stream);

    // symbolic-branch preprocessing
    hipLaunchKernelGGL(k_wgt, dim3(16, 16), dim3(32, 32), 0, stream, Wg, WgT, batch_vec, cnts);
    hipLaunchKernelGGL(k_deg, dim3(4096), dim3(256), 0, stream, edge_index, deg);
    hipLaunchKernelGGL(k_scan, dim3(1), dim3(1024), 0, stream, deg, row_ptr, dis);
    hipLaunchKernelGGL(k_scatter, dim3(4096), dim3(256), 0, stream, edge_index, row_ptr, fill, srcs);
    hipLaunchKernelGGL(k_gemm, dim3(N_NODES / 128, PD / 256), dim3(256), 0, stream,
                       x_nodes, WgT, dis, hn4);
    hipLaunchKernelGGL(k_agg, dim3(N_NODES / NPB), dim3(256), 0, stream,
                       hn4, dis, bg, row_ptr, srcs, batch_vec, sums);

    // implicit branch: fused img+txt projections
    hipLaunchKernelGGL(k_lin_part_it, dim3(BATCH, 6), dim3(256), 0, stream,
                       image_features, text_features, W_img, W_txt, Ppart);
    hipLaunchKernelGGL(k_lin_red_it, dim3(BATCH, 2), dim3(256), 0, stream,
                       Ppart, b_img, b_txt, combined);
    // classifier layer 1 (K=1024) + dot fused
    hipLaunchKernelGGL(k_lin_part, dim3(BATCH, 4), dim3(256), 0, stream,
                       combined, W1, Ppart, 1024);
    hipLaunchKernelGGL(k_reddot, dim3(BATCH), dim3(256), 0, stream,
                       Ppart, b1, W2, b2, yi, 4, (const int*)nullptr);

    // symbolic classifier (mean-pool folded via cnts), K=512, + dot fused
    hipLaunchKernelGGL(k_lin_part, dim3(BATCH, 2), dim3(256), 0, stream,
                       sums, Ws1, Ppart, PD);
    hipLaunchKernelGGL(k_reddot, dim3(BATCH), dim3(256), 0, stream,
                       Ppart, bs1, Ws2, bs2, ys, 2, cnts);

    // fuse
    hipLaunchKernelGGL(k_final, dim3(1), dim3(128), 0, stream, yi, ys, answer, out);
}